// Round 4
// baseline (128.046 us; speedup 1.0000x reference)
//
#include <hip/hip_runtime.h>
#include <math.h>

#define B_ROWS 4096
#define T_COLS 4096
#define NTHREADS 1024
#define NWAVES (NTHREADS / 64)   // 16
#define RPB 8                    // rows per block, one per pipelined iteration
#define NBLOCKS (B_ROWS / RPB)   // 512 blocks = 2/CU: whole grid resident, no generations

// Force a (wave-uniform) float into an SGPR.
__device__ __forceinline__ float rfl(float v) {
    return __int_as_float(__builtin_amdgcn_readfirstlane(__float_as_int(v)));
}

// Barrier that waits on LDS ops only: prefetched global loads stay in flight.
// Inline-asm carries the lgkmcnt wait; the barrier itself is the builtin so the
// compiler treats it as convergent control flow (rule #18: never hide a barrier
// inside opaque asm).
__device__ __forceinline__ void lds_barrier() {
    asm volatile("s_waitcnt lgkmcnt(0)" ::: "memory");
    __builtin_amdgcn_s_barrier();
}

__global__ __launch_bounds__(NTHREADS, 8) void garch_fused(
    const float* __restrict__ x,
    const float* __restrict__ p_omega_log,
    const float* __restrict__ p_alpha_log,
    const float* __restrict__ p_beta_log,
    float* __restrict__ out)
{
    // Double-buffered cross-wave handoff state (g&1): 2 x 4 x 16 floats = 512 B.
    // Two-buffer safety: a wave can only re-write buffer b (iter g+2) after
    // passing barrier g+1, which every reader of buffer b (iter g) reached only
    // after finishing its reads.
    __shared__ float wA[2][NWAVES], wB[2][NWAVES];
    __shared__ float rSum[2][NWAVES], rSsq[2][NWAVES];

    const int t    = threadIdx.x;
    const int lane = t & 63;
    const int wv   = t >> 6;
    const long row0 = (long)blockIdx.x * RPB;

    // ---- Prologue: issue row-0 loads immediately ----
    float4 vc = reinterpret_cast<const float4*>(x + row0 * T_COLS)[t];
    float pg = 0.0f;
    if (lane == 0 && t > 0) pg = x[row0 * T_COLS + 4 * t - 1];

    // ---- Uniform scalar parameter work -> SGPRs (overlaps row-0 load) ----
    float ea_p  = expf(p_alpha_log[0]);
    float eb_p  = expf(p_beta_log[0]);
    float denom = 1.0f + ea_p + eb_p;
    float omega = rfl(expf(p_omega_log[0]));
    float alpha = rfl(ea_p / denom);
    float beta  = rfl(eb_p / denom);
    float beta3 = beta * beta * beta;
    float beta4 = beta3 * beta;

#pragma unroll
    for (int g = 0; g < RPB; ++g) {
        const long row = row0 + g;

        // ---- Prefetch row g+1 BEFORE row g's compute. The lds_barrier below
        // does not drain vmcnt, so these loads stay in flight across it and the
        // memory pipe streams continuously across iterations. ----
        float4 vn = make_float4(0.0f, 0.0f, 0.0f, 0.0f);
        float pgn = 0.0f;
        if (g + 1 < RPB) {
            vn = reinterpret_cast<const float4*>(x + (row + 1) * T_COLS)[t];
            if (lane == 0 && t > 0) pgn = x[(row + 1) * T_COLS + 4 * t - 1];
        }

        float x0 = vc.x, x1 = vc.y, x2 = vc.z, x3 = vc.w;

        // prev = x[4t-1]: lane-1's x3, or the boundary scalar load.
        float prev = __shfl_up(x3, 1);
        if (lane == 0) prev = pg;

        // Per-thread sum/ssq.
        float s1 = (x0 + x1) + (x2 + x3);
        float s2 = x0 * x0;
        s2 = fmaf(x1, x1, s2);
        s2 = fmaf(x2, x2, s2);
        s2 = fmaf(x3, x3, s2);

        // Zero-init affine recurrence partial over this 4-element segment.
        // t>0 : 4 steps (prev, x0, x1, x2) -> a = beta^4
        // t==0: 3 steps (x0, x1, x2)       -> a = beta^3
        float z = (t > 0) ? fmaf(alpha, prev * prev, omega) : 0.0f;
        z = fmaf(beta, z, fmaf(alpha, x0 * x0, omega));
        z = fmaf(beta, z, fmaf(alpha, x1 * x1, omega));
        z = fmaf(beta, z, fmaf(alpha, x2 * x2, omega));
        float ib = z;
        float ia = (t == 0) ? beta3 : beta4;

        // Wave-level reduction (sum, ssq).
#pragma unroll
        for (int d = 32; d > 0; d >>= 1) {
            s1 += __shfl_xor(s1, d);
            s2 += __shfl_xor(s2, d);
        }

        // Wave-level inclusive affine scan over (ia, ib).
#pragma unroll
        for (int d = 1; d < 64; d <<= 1) {
            float pa = __shfl_up(ia, d);
            float pb = __shfl_up(ib, d);
            if (lane >= d) { ib = fmaf(ia, pb, ib); ia = ia * pa; }
        }

        // Cross-wave handoff into buffer g&1.
        if (lane == 0)  { rSum[g & 1][wv] = s1; rSsq[g & 1][wv] = s2; }
        if (lane == 63) { wA[g & 1][wv] = ia;   wB[g & 1][wv] = ib;  }

        lds_barrier();   // LDS visibility only; vmcnt NOT drained.

        // Block-wide variance from the 16 wave partials (broadcast b128 reads).
        float tsum = 0.0f, tssq = 0.0f;
#pragma unroll
        for (int w4 = 0; w4 < NWAVES / 4; ++w4) {
            float4 a = *reinterpret_cast<const float4*>(&rSum[g & 1][4 * w4]);
            float4 b = *reinterpret_cast<const float4*>(&rSsq[g & 1][4 * w4]);
            tsum += (a.x + a.y) + (a.z + a.w);
            tssq += (b.x + b.y) + (b.z + b.w);
        }
        float s0 = (tssq - tsum * tsum * (1.0f / T_COLS)) * (1.0f / (T_COLS - 1));
        s0 = fmaxf(s0, 0.0f);

        // Apply preceding waves' aggregate affine maps to s0.
        float sw = s0;
#pragma unroll
        for (int w = 0; w < NWAVES - 1; ++w)
            if (w < wv) sw = fmaf(wA[g & 1][w], sw, wB[g & 1][w]);

        // Exclusive intra-wave prefix -> entry state s = sigma2_{4t-1}.
        float pea = __shfl_up(ia, 1);
        float peb = __shfl_up(ib, 1);
        if (lane == 0) { pea = 1.0f; peb = 0.0f; }
        float s = fmaf(pea, sw, peb);

        // Recompute the 4-step recurrence from the true entry state.
        float4 q;
        if (t == 0) {
            q.x = __builtin_amdgcn_sqrtf(s);       // sigma2_0 = s0
            float zz = s;
            zz = fmaf(beta, zz, fmaf(alpha, x0 * x0, omega)); q.y = __builtin_amdgcn_sqrtf(zz);
            zz = fmaf(beta, zz, fmaf(alpha, x1 * x1, omega)); q.z = __builtin_amdgcn_sqrtf(zz);
            zz = fmaf(beta, zz, fmaf(alpha, x2 * x2, omega)); q.w = __builtin_amdgcn_sqrtf(zz);
        } else {
            float zz = s;
            zz = fmaf(beta, zz, fmaf(alpha, prev * prev, omega)); q.x = __builtin_amdgcn_sqrtf(zz);
            zz = fmaf(beta, zz, fmaf(alpha, x0 * x0, omega));     q.y = __builtin_amdgcn_sqrtf(zz);
            zz = fmaf(beta, zz, fmaf(alpha, x1 * x1, omega));     q.z = __builtin_amdgcn_sqrtf(zz);
            zz = fmaf(beta, zz, fmaf(alpha, x2 * x2, omega));     q.w = __builtin_amdgcn_sqrtf(zz);
        }

        // Fire-and-forget coalesced store (drained at kernel end, not at barriers).
        reinterpret_cast<float4*>(out + row * T_COLS)[t] = q;

        // Rotate pipeline registers.
        vc = vn; pg = pgn;
    }
}

extern "C" void kernel_launch(void* const* d_in, const int* in_sizes, int n_in,
                              void* d_out, int out_size, void* d_ws, size_t ws_size,
                              hipStream_t stream) {
    const float* x         = (const float*)d_in[0];
    const float* omega_log = (const float*)d_in[1];
    const float* alpha_log = (const float*)d_in[2];
    const float* beta_log  = (const float*)d_in[3];
    float* out = (float*)d_out;

    garch_fused<<<NBLOCKS, NTHREADS, 0, stream>>>(x, omega_log, alpha_log, beta_log, out);
}